// Round 1
// baseline (2693.120 us; speedup 1.0000x reference)
//
#include <hip/hip_runtime.h>

// Problem constants (from reference)
#define N_NODES 100000
#define N_EDGES 1600000
#define EO 48            // EDGE_OUT
constexpr int FEAT = 3 * EO;   // 144
constexpr int HID  = 128;
constexpr int NOUT = 64;

// ---------------- init workspace ----------------
// ws layout: sum[N_NODES*EO] f32 | mx[N_NODES*EO] f32(bits) | cnt[N_NODES] i32
__global__ void init_ws_kernel(float* __restrict__ sum, unsigned int* __restrict__ mx,
                               int* __restrict__ cnt) {
  int i = blockIdx.x * blockDim.x + threadIdx.x;
  const int tot = N_NODES * EO;
  if (i < tot) {
    sum[i] = 0.0f;
    mx[i]  = 0xFF800000u;  // -inf
  }
  if (i < N_NODES) cnt[i] = 0;
}

// float atomic max via signed/unsigned int ordering trick (init must be -inf)
__device__ __forceinline__ void atomicMaxFloat(float* addr, float v) {
  if (__float_as_uint(v) & 0x80000000u) {
    atomicMin((unsigned int*)addr, __float_as_uint(v));  // negative: smaller uint bits = larger float
  } else {
    atomicMax((int*)addr, __float_as_int(v));            // non-negative: int order = float order
  }
}

// ---------------- scatter (sum / max / count) ----------------
// one thread per (edge, 4-feature-group): float4 load, 4+4 atomics
__global__ void scatter_kernel(const float4* __restrict__ ea4, const int* __restrict__ col,
                               float* __restrict__ sum, float* __restrict__ mx,
                               int* __restrict__ cnt) {
  const int total = N_EDGES * (EO / 4);  // 19.2M
  int i = blockIdx.x * blockDim.x + threadIdx.x;
  if (i >= total) return;
  int e = i / (EO / 4);
  int q = i - e * (EO / 4);
  float4 v = ea4[i];
  int d = col[e];
  int base = d * EO + q * 4;
  atomicAdd(&sum[base + 0], v.x);
  atomicAdd(&sum[base + 1], v.y);
  atomicAdd(&sum[base + 2], v.z);
  atomicAdd(&sum[base + 3], v.w);
  atomicMaxFloat(&mx[base + 0], v.x);
  atomicMaxFloat(&mx[base + 1], v.y);
  atomicMaxFloat(&mx[base + 2], v.z);
  atomicMaxFloat(&mx[base + 3], v.w);
  if (q == 0) atomicAdd(&cnt[d], 1);
}

// ---------------- fused feat-build + MLP ----------------
// Per block: 64 nodes. W1 (144x128) + W2 (128x64) + feat tile (64x144) in LDS.
// 512 threads: tx = tid&31 (hidden quad), ty = tid>>5 (node quad of 4 nodes).
__launch_bounds__(512)
__global__ void mlp_kernel(const float* __restrict__ sum, const unsigned int* __restrict__ mxb,
                           const int* __restrict__ cnt,
                           const float* __restrict__ W1, const float* __restrict__ b1,
                           const float* __restrict__ W2, const float* __restrict__ b2,
                           float* __restrict__ out) {
  __shared__ float W1s[FEAT * HID];   // 73728 B
  __shared__ float W2s[HID * NOUT];   // 32768 B
  __shared__ float buf[64 * FEAT];    // 36864 B  (reused as h[64][128] later)

  const int tid = threadIdx.x;
  const int g0  = blockIdx.x * 64;

  for (int i = tid; i < FEAT * HID; i += 512) W1s[i] = W1[i];
  for (int i = tid; i < HID * NOUT; i += 512) W2s[i] = W2[i];

  // build feat tile: [sum | max(-inf->0) | mean]
  for (int i = tid; i < 64 * FEAT; i += 512) {
    int r = i / FEAT, c = i - r * FEAT;
    int g = g0 + r;
    float v = 0.0f;
    if (g < N_NODES) {
      if (c < EO) {
        v = sum[g * EO + c];
      } else if (c < 2 * EO) {
        unsigned int b = mxb[g * EO + (c - EO)];
        v = (b == 0xFF800000u) ? 0.0f : __uint_as_float(b);
      } else {
        int ct = cnt[g];
        v = sum[g * EO + (c - 2 * EO)] / (float)(ct > 1 ? ct : 1);
      }
    }
    buf[i] = v;
  }
  __syncthreads();

  const int tx = tid & 31;   // hidden group: columns tx*4..tx*4+3
  const int ty = tid >> 5;   // node group:   rows   ty*4..ty*4+3

  // GEMM1: h[64][128] = relu(feat @ W1 + b1)
  float acc[4][4];
  {
    const float4 bv = *(const float4*)&b1[tx * 4];
#pragma unroll
    for (int i = 0; i < 4; ++i) {
      acc[i][0] = bv.x; acc[i][1] = bv.y; acc[i][2] = bv.z; acc[i][3] = bv.w;
    }
  }
  for (int k = 0; k < FEAT; ++k) {
    const float4 w = *(const float4*)&W1s[k * HID + tx * 4];
#pragma unroll
    for (int i = 0; i < 4; ++i) {
      float f = buf[(ty * 4 + i) * FEAT + k];
      acc[i][0] += f * w.x; acc[i][1] += f * w.y;
      acc[i][2] += f * w.z; acc[i][3] += f * w.w;
    }
  }
  __syncthreads();  // everyone done reading feat before overwrite

  // relu -> h into buf as [64][128]
#pragma unroll
  for (int i = 0; i < 4; ++i) {
    float4 hv;
    hv.x = fmaxf(acc[i][0], 0.0f); hv.y = fmaxf(acc[i][1], 0.0f);
    hv.z = fmaxf(acc[i][2], 0.0f); hv.w = fmaxf(acc[i][3], 0.0f);
    *(float4*)&buf[(ty * 4 + i) * HID + tx * 4] = hv;
  }
  __syncthreads();

  // GEMM2: out[64][64] = h @ W2 + b2
  float acc2[4][2];
  {
    const float2 bv = *(const float2*)&b2[tx * 2];
#pragma unroll
    for (int i = 0; i < 4; ++i) { acc2[i][0] = bv.x; acc2[i][1] = bv.y; }
  }
  for (int k = 0; k < HID; ++k) {
    const float2 w = *(const float2*)&W2s[k * NOUT + tx * 2];
#pragma unroll
    for (int i = 0; i < 4; ++i) {
      float h = buf[(ty * 4 + i) * HID + k];
      acc2[i][0] += h * w.x; acc2[i][1] += h * w.y;
    }
  }
#pragma unroll
  for (int i = 0; i < 4; ++i) {
    int g = g0 + ty * 4 + i;
    if (g < N_NODES) {
      *(float2*)&out[g * NOUT + tx * 2] = make_float2(acc2[i][0], acc2[i][1]);
    }
  }
}

extern "C" void kernel_launch(void* const* d_in, const int* in_sizes, int n_in,
                              void* d_out, int out_size, void* d_ws, size_t ws_size,
                              hipStream_t stream) {
  // inputs: 0:x 1:edge_index(2,E) 2:edge_attr(E,48) 3:u 4:batch 5:W1 6:b1 7:W2 8:b2
  const int*   eidx = (const int*)d_in[1];
  const float* ea   = (const float*)d_in[2];
  const float* W1   = (const float*)d_in[5];
  const float* b1   = (const float*)d_in[6];
  const float* W2   = (const float*)d_in[7];
  const float* b2   = (const float*)d_in[8];
  const int* col = eidx + N_EDGES;  // edge_index[1]
  float* out = (float*)d_out;

  // ws layout
  float*        sum = (float*)d_ws;                       // 4.8M f32
  unsigned int* mxb = (unsigned int*)(sum + N_NODES * EO); // 4.8M
  int*          cnt = (int*)(mxb + N_NODES * EO);          // 100K
  // total ~38.8 MB of ws

  {
    int tot = N_NODES * EO;
    init_ws_kernel<<<(tot + 255) / 256, 256, 0, stream>>>(sum, mxb, cnt);
  }
  {
    int tot = N_EDGES * (EO / 4);
    scatter_kernel<<<(tot + 255) / 256, 256, 0, stream>>>(
        (const float4*)ea, col, sum, (float*)mxb, cnt);
  }
  {
    int nblk = (N_NODES + 63) / 64;  // 1563
    mlp_kernel<<<nblk, 512, 0, stream>>>(sum, mxb, cnt, W1, b1, W2, b2, out);
  }
}

// Round 2
// 600.849 us; speedup vs baseline: 4.4822x; 4.4822x over previous
//
#include <hip/hip_runtime.h>
#include <math.h>

// Problem constants (from reference)
#define N_NODES 100000
#define N_EDGES 1600000
#define EO 48            // EDGE_OUT
constexpr int FEAT = 3 * EO;   // 144
constexpr int HID  = 128;
constexpr int NOUT = 64;
constexpr int SCAN_BLK = 1024;                              // elements per scan block
constexpr int NB1 = (N_NODES + SCAN_BLK - 1) / SCAN_BLK;    // 98

// ---------------- counting sort by destination ----------------

__global__ void zero_cnt_kernel(int* __restrict__ cnt) {
  int i = blockIdx.x * blockDim.x + threadIdx.x;
  if (i < N_NODES) cnt[i] = 0;
}

__global__ void count_kernel(const int* __restrict__ col, int* __restrict__ cnt) {
  int e = blockIdx.x * blockDim.x + threadIdx.x;
  if (e < N_EDGES) atomicAdd(&cnt[col[e]], 1);
}

// per-block exclusive scan over 1024 elements (256 thr x 4), emits block sums
__global__ void scan1_kernel(const int* __restrict__ cnt, int* __restrict__ pre,
                             int* __restrict__ bsum) {
  __shared__ int s[256];
  int tid = threadIdx.x;
  int base = blockIdx.x * SCAN_BLK + tid * 4;
  int v[4]; int t = 0;
#pragma unroll
  for (int j = 0; j < 4; ++j) {
    int idx = base + j;
    v[j] = (idx < N_NODES) ? cnt[idx] : 0;
    t += v[j];
  }
  s[tid] = t;
  __syncthreads();
  for (int off = 1; off < 256; off <<= 1) {
    int x = (tid >= off) ? s[tid - off] : 0;
    __syncthreads();
    s[tid] += x;
    __syncthreads();
  }
  int excl = s[tid] - t;
  if (tid == 255) bsum[blockIdx.x] = s[tid];
  int run = excl;
#pragma unroll
  for (int j = 0; j < 4; ++j) {
    int idx = base + j;
    if (idx < N_NODES) pre[idx] = run;
    run += v[j];
  }
}

// scan of the NB1 block sums (single block)
__global__ void scan2_kernel(const int* __restrict__ bsum, int* __restrict__ boff) {
  __shared__ int s[128];
  int tid = threadIdx.x;
  int t = (tid < NB1) ? bsum[tid] : 0;
  s[tid] = t;
  __syncthreads();
  for (int off = 1; off < 128; off <<= 1) {
    int x = (tid >= off) ? s[tid - off] : 0;
    __syncthreads();
    s[tid] += x;
    __syncthreads();
  }
  if (tid < NB1) boff[tid] = s[tid] - t;
}

// combine -> segment starts; also init cursor copy for the id scatter
__global__ void scan3_kernel(const int* __restrict__ pre, const int* __restrict__ boff,
                             int* __restrict__ off, int* __restrict__ cursor) {
  int i = blockIdx.x * blockDim.x + threadIdx.x;
  if (i < N_NODES) {
    int o = pre[i] + boff[i >> 10];
    off[i] = o;
    cursor[i] = o;
  }
}

__global__ void scatter_ids_kernel(const int* __restrict__ col, int* __restrict__ cursor,
                                   int* __restrict__ sorted_eid) {
  int e = blockIdx.x * blockDim.x + threadIdx.x;
  if (e < N_EDGES) {
    int d = col[e];
    int pos = atomicAdd(&cursor[d], 1);
    sorted_eid[pos] = e;
  }
}

// ---------------- fused gather-reduce + MLP ----------------
// Per block: 64 nodes. Phase 1: wave w (of 8) reduces nodes w*8..w*8+7;
// lanes 0..47 each own one feature, loop the node's edge segment.
// Phase 2: the verified 4x4-register-tile MLP (144->128 relu ->64).
__launch_bounds__(512)
__global__ void fused_mlp_kernel(const float* __restrict__ ea, const int* __restrict__ sorted_eid,
                                 const int* __restrict__ off, const int* __restrict__ cnt,
                                 const float* __restrict__ W1, const float* __restrict__ b1,
                                 const float* __restrict__ W2, const float* __restrict__ b2,
                                 float* __restrict__ out) {
  __shared__ float W1s[FEAT * HID];   // 73728 B
  __shared__ float W2s[HID * NOUT];   // 32768 B
  __shared__ float buf[64 * FEAT];    // 36864 B (feat tile, reused as h[64][128])

  const int tid = threadIdx.x;
  const int g0  = blockIdx.x * 64;

  for (int i = tid; i < FEAT * HID; i += 512) W1s[i] = W1[i];
  for (int i = tid; i < HID * NOUT; i += 512) W2s[i] = W2[i];

  const int w    = tid >> 6;   // wave id 0..7
  const int lane = tid & 63;

#pragma unroll
  for (int i = 0; i < 8; ++i) {
    int r = w * 8 + i;
    int g = g0 + r;
    if (lane < EO) {
      float s = 0.0f, m = -INFINITY;
      int deg = 0, st = 0;
      if (g < N_NODES) { deg = cnt[g]; st = off[g]; }
#pragma unroll 4
      for (int j = 0; j < deg; ++j) {
        int eid = sorted_eid[st + j];     // uniform per wave -> broadcast
        float v = ea[eid * EO + lane];    // 192B coalesced row read
        s += v;
        m = fmaxf(m, v);
      }
      if (deg == 0) m = 0.0f;             // torch_scatter empty-segment -> 0
      float mean = s / (float)(deg > 0 ? deg : 1);
      buf[r * FEAT + lane]          = s;
      buf[r * FEAT + EO + lane]     = m;
      buf[r * FEAT + 2 * EO + lane] = mean;
    }
  }
  __syncthreads();

  const int tx = tid & 31;   // hidden quad: cols tx*4..tx*4+3
  const int ty = tid >> 5;   // node quad:   rows ty*4..ty*4+3

  // GEMM1: h[64][128] = relu(feat @ W1 + b1)
  float acc[4][4];
  {
    const float4 bv = *(const float4*)&b1[tx * 4];
#pragma unroll
    for (int i = 0; i < 4; ++i) {
      acc[i][0] = bv.x; acc[i][1] = bv.y; acc[i][2] = bv.z; acc[i][3] = bv.w;
    }
  }
  for (int k = 0; k < FEAT; ++k) {
    const float4 wv = *(const float4*)&W1s[k * HID + tx * 4];
#pragma unroll
    for (int i = 0; i < 4; ++i) {
      float f = buf[(ty * 4 + i) * FEAT + k];
      acc[i][0] += f * wv.x; acc[i][1] += f * wv.y;
      acc[i][2] += f * wv.z; acc[i][3] += f * wv.w;
    }
  }
  __syncthreads();  // done reading feat before overwrite

#pragma unroll
  for (int i = 0; i < 4; ++i) {
    float4 hv;
    hv.x = fmaxf(acc[i][0], 0.0f); hv.y = fmaxf(acc[i][1], 0.0f);
    hv.z = fmaxf(acc[i][2], 0.0f); hv.w = fmaxf(acc[i][3], 0.0f);
    *(float4*)&buf[(ty * 4 + i) * HID + tx * 4] = hv;
  }
  __syncthreads();

  // GEMM2: out[64][64] = h @ W2 + b2
  float acc2[4][2];
  {
    const float2 bv = *(const float2*)&b2[tx * 2];
#pragma unroll
    for (int i = 0; i < 4; ++i) { acc2[i][0] = bv.x; acc2[i][1] = bv.y; }
  }
  for (int k = 0; k < HID; ++k) {
    const float2 wv = *(const float2*)&W2s[k * NOUT + tx * 2];
#pragma unroll
    for (int i = 0; i < 4; ++i) {
      float h = buf[(ty * 4 + i) * HID + k];
      acc2[i][0] += h * wv.x; acc2[i][1] += h * wv.y;
    }
  }
#pragma unroll
  for (int i = 0; i < 4; ++i) {
    int g = g0 + ty * 4 + i;
    if (g < N_NODES) {
      *(float2*)&out[g * NOUT + tx * 2] = make_float2(acc2[i][0], acc2[i][1]);
    }
  }
}

extern "C" void kernel_launch(void* const* d_in, const int* in_sizes, int n_in,
                              void* d_out, int out_size, void* d_ws, size_t ws_size,
                              hipStream_t stream) {
  // inputs: 0:x 1:edge_index(2,E) 2:edge_attr(E,48) 3:u 4:batch 5:W1 6:b1 7:W2 8:b2
  const int*   eidx = (const int*)d_in[1];
  const float* ea   = (const float*)d_in[2];
  const float* W1   = (const float*)d_in[5];
  const float* b1   = (const float*)d_in[6];
  const float* W2   = (const float*)d_in[7];
  const float* b2   = (const float*)d_in[8];
  const int* col = eidx + N_EDGES;  // edge_index[1]
  float* out = (float*)d_out;

  // ws layout (ints): cnt | pre | off | cursor | bsum | boff | sorted_eid
  int* cnt    = (int*)d_ws;
  int* pre    = cnt + N_NODES;
  int* off    = pre + N_NODES;
  int* cursor = off + N_NODES;
  int* bsum   = cursor + N_NODES;
  int* boff   = bsum + NB1;
  int* sorted_eid = boff + NB1;     // 1.6M ints; total ~8 MB of ws

  zero_cnt_kernel<<<(N_NODES + 255) / 256, 256, 0, stream>>>(cnt);
  count_kernel<<<(N_EDGES + 255) / 256, 256, 0, stream>>>(col, cnt);
  scan1_kernel<<<NB1, 256, 0, stream>>>(cnt, pre, bsum);
  scan2_kernel<<<1, 128, 0, stream>>>(bsum, boff);
  scan3_kernel<<<(N_NODES + 255) / 256, 256, 0, stream>>>(pre, boff, off, cursor);
  scatter_ids_kernel<<<(N_EDGES + 255) / 256, 256, 0, stream>>>(col, cursor, sorted_eid);
  fused_mlp_kernel<<<(N_NODES + 63) / 64, 512, 0, stream>>>(
      ea, sorted_eid, off, cnt, W1, b1, W2, b2, out);
}

// Round 3
// 347.214 us; speedup vs baseline: 7.7564x; 1.7305x over previous
//
#include <hip/hip_runtime.h>
#include <math.h>

#define N_NODES 100000
#define N_EDGES 1600000
#define EO 48
constexpr int FEAT = 3 * EO;   // 144
constexpr int K1   = 160;      // zero-padded K for GEMM1 (W1T padded)
constexpr int HID  = 128;
constexpr int NOUT = 64;
constexpr int SCAN_BLK = 1024;
constexpr int NB1 = (N_NODES + SCAN_BLK - 1) / SCAN_BLK;    // 98
constexpr int FEAT_ROWS_ALLOC = 100048;                      // 64-pad + next-row slack

typedef __attribute__((ext_vector_type(8))) short short8;   // 8 bf16
typedef __attribute__((ext_vector_type(4))) float floatx4;

__device__ __forceinline__ unsigned short f2bf(float f) {
  unsigned int u = __float_as_uint(f);
  unsigned int r = (u + 0x7fffu + ((u >> 16) & 1u)) >> 16;   // RNE
  return (unsigned short)r;
}

// ---------------- counting sort by destination ----------------
__global__ void zero_cnt_kernel(int* __restrict__ cnt) {
  int i = blockIdx.x * blockDim.x + threadIdx.x;
  if (i < N_NODES) cnt[i] = 0;
}

__global__ void count_kernel(const int* __restrict__ col, int* __restrict__ cnt) {
  int e = blockIdx.x * blockDim.x + threadIdx.x;
  if (e < N_EDGES) atomicAdd(&cnt[col[e]], 1);
}

__global__ void scan1_kernel(const int* __restrict__ cnt, int* __restrict__ pre,
                             int* __restrict__ bsum) {
  __shared__ int s[256];
  int tid = threadIdx.x;
  int base = blockIdx.x * SCAN_BLK + tid * 4;
  int v[4]; int t = 0;
#pragma unroll
  for (int j = 0; j < 4; ++j) {
    int idx = base + j;
    v[j] = (idx < N_NODES) ? cnt[idx] : 0;
    t += v[j];
  }
  s[tid] = t;
  __syncthreads();
  for (int off = 1; off < 256; off <<= 1) {
    int x = (tid >= off) ? s[tid - off] : 0;
    __syncthreads();
    s[tid] += x;
    __syncthreads();
  }
  int excl = s[tid] - t;
  if (tid == 255) bsum[blockIdx.x] = s[tid];
  int run = excl;
#pragma unroll
  for (int j = 0; j < 4; ++j) {
    int idx = base + j;
    if (idx < N_NODES) pre[idx] = run;
    run += v[j];
  }
}

__global__ void scan2_kernel(const int* __restrict__ bsum, int* __restrict__ boff) {
  __shared__ int s[128];
  int tid = threadIdx.x;
  int t = (tid < NB1) ? bsum[tid] : 0;
  s[tid] = t;
  __syncthreads();
  for (int off = 1; off < 128; off <<= 1) {
    int x = (tid >= off) ? s[tid - off] : 0;
    __syncthreads();
    s[tid] += x;
    __syncthreads();
  }
  if (tid < NB1) boff[tid] = s[tid] - t;
}

__global__ void scan3_kernel(const int* __restrict__ pre, const int* __restrict__ boff,
                             int* __restrict__ off, int* __restrict__ cursor) {
  int i = blockIdx.x * blockDim.x + threadIdx.x;
  if (i < N_NODES) {
    int o = pre[i] + boff[i >> 10];
    off[i] = o;
    cursor[i] = o;
  }
}

__global__ void scatter_ids_kernel(const int* __restrict__ col, int* __restrict__ cursor,
                                   int* __restrict__ sorted_eid) {
  int e = blockIdx.x * blockDim.x + threadIdx.x;
  if (e < N_EDGES) {
    int d = col[e];
    int pos = atomicAdd(&cursor[d], 1);
    sorted_eid[pos] = e;
  }
}

// ---------------- weight prep: bf16 transposed [col][k] ----------------
__global__ void prep_w_kernel(const float* __restrict__ W1, const float* __restrict__ W2,
                              unsigned short* __restrict__ W1T, unsigned short* __restrict__ W2T) {
  int i = blockIdx.x * blockDim.x + threadIdx.x;
  if (i < HID * K1) {
    int c = i / K1, k = i - c * K1;
    W1T[i] = (k < FEAT) ? f2bf(W1[k * HID + c]) : (unsigned short)0;
  } else {
    int j = i - HID * K1;
    if (j < NOUT * HID) {
      int c = j / HID, k = j - c * HID;
      W2T[j] = f2bf(W2[k * NOUT + c]);
    }
  }
}

// ---------------- gather-reduce: one wave per node ----------------
// feat row (bf16): [sum(48) | max(48) | mean(48)], row stride FEAT=144
__launch_bounds__(256)
__global__ void gather_kernel(const float* __restrict__ ea,
                              const int* __restrict__ sorted_eid,
                              const int* __restrict__ off,
                              const int* __restrict__ cnt,
                              unsigned short* __restrict__ featbf) {
  const int wid  = threadIdx.x >> 6;
  const int lane = threadIdx.x & 63;
  const int g = blockIdx.x * 4 + wid;
  if (g >= N_NODES) return;

  const int deg = cnt[g];
  const int st  = off[g];
  float s = 0.0f, m = -INFINITY;

  for (int base = 0; base < deg; base += 64) {
    int n = deg - base;
    if (n > 64) n = 64;
    // one coalesced load of up to 64 edge ids, broadcast via shfl
    int eidv = sorted_eid[st + base + (lane < n ? lane : n - 1)];
    int t = 0;
    for (; t + 4 <= n; t += 4) {
      int e0 = __shfl(eidv, t);
      int e1 = __shfl(eidv, t + 1);
      int e2 = __shfl(eidv, t + 2);
      int e3 = __shfl(eidv, t + 3);
      if (lane < EO) {
        float v0 = ea[e0 * EO + lane];
        float v1 = ea[e1 * EO + lane];
        float v2 = ea[e2 * EO + lane];
        float v3 = ea[e3 * EO + lane];
        s += (v0 + v1) + (v2 + v3);
        m = fmaxf(m, fmaxf(fmaxf(v0, v1), fmaxf(v2, v3)));
      }
    }
    for (; t < n; ++t) {
      int e = __shfl(eidv, t);
      if (lane < EO) {
        float v = ea[e * EO + lane];
        s += v;
        m = fmaxf(m, v);
      }
    }
  }

  if (lane < EO) {
    if (deg == 0) m = 0.0f;
    float mean = s / (float)(deg > 0 ? deg : 1);
    unsigned short* row = featbf + (size_t)g * FEAT;
    row[lane]          = f2bf(s);
    row[EO + lane]     = f2bf(m);
    row[2 * EO + lane] = f2bf(mean);
  }
}

// ---------------- MFMA MLP: 64 nodes/block, 4 waves, 16 nodes/wave ----------------
__launch_bounds__(256)
__global__ void mlp_kernel(const unsigned short* __restrict__ featbf,
                           const unsigned short* __restrict__ W1T,
                           const unsigned short* __restrict__ W2T,
                           const float* __restrict__ b1,
                           const float* __restrict__ b2,
                           float* __restrict__ out) {
  __shared__ unsigned short h_lds[64][HID + 8];   // +8 pad: 272B rows -> conflict-free-ish

  const int tid  = threadIdx.x;
  const int w    = tid >> 6;     // wave 0..3
  const int lane = tid & 63;
  const int llo  = lane & 15;    // A row / B col / C col
  const int lhi  = lane >> 4;    // k-group / C row-group

  const int g0   = blockIdx.x * 64;
  int rowA = g0 + w * 16 + llo;  // A rows; may exceed N (slack rows allocated)

  // ---- GEMM1: h[16 x 128] = feat[16 x 144] @ W1 + b1, K padded to 160 ----
  floatx4 acc[8];
#pragma unroll
  for (int c = 0; c < 8; ++c) acc[c] = (floatx4)0.0f;

  const unsigned short* arow = featbf + (size_t)rowA * FEAT;
#pragma unroll
  for (int ks = 0; ks < 5; ++ks) {
    // ks=4 reads 16 bf16 starting at k=128: elems 144..159 spill into next row,
    // multiplied by W1T's zero pad -> contributes 0.
    short8 afrag = *(const short8*)(arow + ks * 32 + lhi * 8);
#pragma unroll
    for (int c = 0; c < 8; ++c) {
      short8 bfrag = *(const short8*)(W1T + (size_t)(c * 16 + llo) * K1 + ks * 32 + lhi * 8);
      acc[c] = __builtin_amdgcn_mfma_f32_16x16x32_bf16(afrag, bfrag, acc[c], 0, 0, 0);
    }
  }

  // epilogue 1: bias + relu -> bf16 -> LDS (C layout: col=llo, row=lhi*4+r)
#pragma unroll
  for (int c = 0; c < 8; ++c) {
    int col = c * 16 + llo;
    float bias = b1[col];
#pragma unroll
    for (int r = 0; r < 4; ++r) {
      int row = w * 16 + lhi * 4 + r;
      h_lds[row][col] = f2bf(fmaxf(acc[c][r] + bias, 0.0f));
    }
  }
  __syncthreads();

  // ---- GEMM2: out[16 x 64] = h[16 x 128] @ W2 + b2 ----
  floatx4 acc2[4];
#pragma unroll
  for (int c = 0; c < 4; ++c) acc2[c] = (floatx4)0.0f;

#pragma unroll
  for (int ks = 0; ks < 4; ++ks) {
    short8 afrag = *(const short8*)&h_lds[w * 16 + llo][ks * 32 + lhi * 8];
#pragma unroll
    for (int c = 0; c < 4; ++c) {
      short8 bfrag = *(const short8*)(W2T + (size_t)(c * 16 + llo) * HID + ks * 32 + lhi * 8);
      acc2[c] = __builtin_amdgcn_mfma_f32_16x16x32_bf16(afrag, bfrag, acc2[c], 0, 0, 0);
    }
  }

#pragma unroll
  for (int c = 0; c < 4; ++c) {
    int col = c * 16 + llo;
    float bias = b2[col];
#pragma unroll
    for (int r = 0; r < 4; ++r) {
      int g = g0 + w * 16 + lhi * 4 + r;
      if (g < N_NODES) out[(size_t)g * NOUT + col] = acc2[c][r] + bias;
    }
  }
}

extern "C" void kernel_launch(void* const* d_in, const int* in_sizes, int n_in,
                              void* d_out, int out_size, void* d_ws, size_t ws_size,
                              hipStream_t stream) {
  // inputs: 0:x 1:edge_index(2,E) 2:edge_attr(E,48) 3:u 4:batch 5:W1 6:b1 7:W2 8:b2
  const int*   eidx = (const int*)d_in[1];
  const float* ea   = (const float*)d_in[2];
  const float* W1   = (const float*)d_in[5];
  const float* b1   = (const float*)d_in[6];
  const float* W2   = (const float*)d_in[7];
  const float* b2   = (const float*)d_in[8];
  const int* col = eidx + N_EDGES;  // edge_index[1]
  float* out = (float*)d_out;

  // ws layout (bytes):
  char* p = (char*)d_ws;
  int* cnt    = (int*)p;  p += (size_t)N_NODES * 4;
  int* pre    = (int*)p;  p += (size_t)N_NODES * 4;
  int* off    = (int*)p;  p += (size_t)N_NODES * 4;
  int* cursor = (int*)p;  p += (size_t)N_NODES * 4;
  int* bsum   = (int*)p;  p += 512;
  int* boff   = (int*)p;  p += 512;
  int* sorted_eid = (int*)p;  p += (size_t)N_EDGES * 4;
  unsigned short* featbf = (unsigned short*)p;  p += (size_t)FEAT_ROWS_ALLOC * FEAT * 2;
  unsigned short* W1T = (unsigned short*)p;     p += (size_t)HID * K1 * 2;
  unsigned short* W2T = (unsigned short*)p;     // + 64*128*2 ; total ~36.9 MB

  zero_cnt_kernel<<<(N_NODES + 255) / 256, 256, 0, stream>>>(cnt);
  count_kernel<<<(N_EDGES + 255) / 256, 256, 0, stream>>>(col, cnt);
  scan1_kernel<<<NB1, 256, 0, stream>>>(cnt, pre, bsum);
  scan2_kernel<<<1, 128, 0, stream>>>(bsum, boff);
  scan3_kernel<<<(N_NODES + 255) / 256, 256, 0, stream>>>(pre, boff, off, cursor);
  scatter_ids_kernel<<<(N_EDGES + 255) / 256, 256, 0, stream>>>(col, cursor, sorted_eid);
  prep_w_kernel<<<(HID * K1 + NOUT * HID + 255) / 256, 256, 0, stream>>>(W1, W2, W1T, W2T);
  gather_kernel<<<(N_NODES + 3) / 4, 256, 0, stream>>>(ea, sorted_eid, off, cnt, featbf);
  mlp_kernel<<<(N_NODES + 63) / 64, 256, 0, stream>>>(featbf, W1T, W2T, b1, b2, out);
}

// Round 4
// 329.672 us; speedup vs baseline: 8.1691x; 1.0532x over previous
//
#include <hip/hip_runtime.h>
#include <math.h>

#define N_NODES 100000
#define N_EDGES 1600000
#define EO 48
constexpr int FEAT = 3 * EO;   // 144
constexpr int K1   = 160;      // zero-padded K for GEMM1 (W1T padded)
constexpr int HID  = 128;
constexpr int NOUT = 64;
constexpr int SCAN_BLK = 1024;
constexpr int NB1 = (N_NODES + SCAN_BLK - 1) / SCAN_BLK;    // 98
constexpr int FEAT_ROWS_ALLOC = 100048;

typedef __attribute__((ext_vector_type(8))) short short8;   // 8 bf16
typedef __attribute__((ext_vector_type(4))) float floatx4;

__device__ __forceinline__ unsigned short f2bf(float f) {
  unsigned int u = __float_as_uint(f);
  unsigned int r = (u + 0x7fffu + ((u >> 16) & 1u)) >> 16;   // RNE
  return (unsigned short)r;
}

// ---------------- init: zero cnt + prep bf16 transposed weights ----------------
__global__ void init_prep_kernel(int* __restrict__ cnt,
                                 const float* __restrict__ W1, const float* __restrict__ W2,
                                 unsigned short* __restrict__ W1T, unsigned short* __restrict__ W2T) {
  int i = blockIdx.x * blockDim.x + threadIdx.x;
  if (i < N_NODES) cnt[i] = 0;
  if (i < HID * K1) {
    int c = i / K1, k = i - c * K1;
    W1T[i] = (k < FEAT) ? f2bf(W1[k * HID + c]) : (unsigned short)0;
  } else {
    int j = i - HID * K1;
    if (j < NOUT * HID) {
      int c = j / HID, k = j - c * HID;
      W2T[j] = f2bf(W2[k * NOUT + c]);
    }
  }
}

// ---------------- counting sort by destination ----------------
__global__ void count_kernel(const int4* __restrict__ col4, int* __restrict__ cnt) {
  int i = blockIdx.x * blockDim.x + threadIdx.x;
  if (i < N_EDGES / 4) {
    int4 c = col4[i];
    atomicAdd(&cnt[c.x], 1);
    atomicAdd(&cnt[c.y], 1);
    atomicAdd(&cnt[c.z], 1);
    atomicAdd(&cnt[c.w], 1);
  }
}

__global__ void scan1_kernel(const int* __restrict__ cnt, int* __restrict__ pre,
                             int* __restrict__ bsum) {
  __shared__ int s[256];
  int tid = threadIdx.x;
  int base = blockIdx.x * SCAN_BLK + tid * 4;
  int v[4]; int t = 0;
#pragma unroll
  for (int j = 0; j < 4; ++j) {
    int idx = base + j;
    v[j] = (idx < N_NODES) ? cnt[idx] : 0;
    t += v[j];
  }
  s[tid] = t;
  __syncthreads();
  for (int off = 1; off < 256; off <<= 1) {
    int x = (tid >= off) ? s[tid - off] : 0;
    __syncthreads();
    s[tid] += x;
    __syncthreads();
  }
  int excl = s[tid] - t;
  if (tid == 255) bsum[blockIdx.x] = s[tid];
  int run = excl;
#pragma unroll
  for (int j = 0; j < 4; ++j) {
    int idx = base + j;
    if (idx < N_NODES) pre[idx] = run;
    run += v[j];
  }
}

__global__ void scan2_kernel(const int* __restrict__ bsum, int* __restrict__ boff) {
  __shared__ int s[128];
  int tid = threadIdx.x;
  int t = (tid < NB1) ? bsum[tid] : 0;
  s[tid] = t;
  __syncthreads();
  for (int off = 1; off < 128; off <<= 1) {
    int x = (tid >= off) ? s[tid - off] : 0;
    __syncthreads();
    s[tid] += x;
    __syncthreads();
  }
  if (tid < NB1) boff[tid] = s[tid] - t;
}

__global__ void scan3_kernel(const int* __restrict__ pre, const int* __restrict__ boff,
                             int* __restrict__ off, int* __restrict__ cursor) {
  int i = blockIdx.x * blockDim.x + threadIdx.x;
  if (i < N_NODES) {
    int o = pre[i] + boff[i >> 10];
    off[i] = o;
    cursor[i] = o;
  }
}

__global__ void scatter_ids_kernel(const int4* __restrict__ col4, int* __restrict__ cursor,
                                   int* __restrict__ sorted_eid) {
  int i = blockIdx.x * blockDim.x + threadIdx.x;
  if (i < N_EDGES / 4) {
    int4 c = col4[i];
    int e = i * 4;
    sorted_eid[atomicAdd(&cursor[c.x], 1)] = e;
    sorted_eid[atomicAdd(&cursor[c.y], 1)] = e + 1;
    sorted_eid[atomicAdd(&cursor[c.z], 1)] = e + 2;
    sorted_eid[atomicAdd(&cursor[c.w], 1)] = e + 3;
  }
}

// ---------------- gather-reduce: one wave per node, 8-deep pipeline ----------------
__launch_bounds__(256)
__global__ void gather_kernel(const float* __restrict__ ea,
                              const int* __restrict__ sorted_eid,
                              const int* __restrict__ off,
                              const int* __restrict__ cnt,
                              unsigned short* __restrict__ featbf) {
  const int wid  = threadIdx.x >> 6;
  const int lane = threadIdx.x & 63;
  const int g = blockIdx.x * 4 + wid;
  if (g >= N_NODES) return;

  const int deg = cnt[g];
  const int st  = off[g];
  float s = 0.0f, m = -INFINITY;

  for (int base = 0; base < deg; base += 64) {
    int n = deg - base;
    if (n > 64) n = 64;
    int eidv = sorted_eid[st + base + (lane < n ? lane : n - 1)];
    int t = 0;
    for (; t + 8 <= n; t += 8) {
      // uniform lane index -> SGPR edge id -> scalar address math, 8 loads in flight
      int e0 = __builtin_amdgcn_readlane(eidv, t + 0);
      int e1 = __builtin_amdgcn_readlane(eidv, t + 1);
      int e2 = __builtin_amdgcn_readlane(eidv, t + 2);
      int e3 = __builtin_amdgcn_readlane(eidv, t + 3);
      int e4 = __builtin_amdgcn_readlane(eidv, t + 4);
      int e5 = __builtin_amdgcn_readlane(eidv, t + 5);
      int e6 = __builtin_amdgcn_readlane(eidv, t + 6);
      int e7 = __builtin_amdgcn_readlane(eidv, t + 7);
      if (lane < EO) {
        float v0 = ea[(size_t)e0 * EO + lane];
        float v1 = ea[(size_t)e1 * EO + lane];
        float v2 = ea[(size_t)e2 * EO + lane];
        float v3 = ea[(size_t)e3 * EO + lane];
        float v4 = ea[(size_t)e4 * EO + lane];
        float v5 = ea[(size_t)e5 * EO + lane];
        float v6 = ea[(size_t)e6 * EO + lane];
        float v7 = ea[(size_t)e7 * EO + lane];
        s += ((v0 + v1) + (v2 + v3)) + ((v4 + v5) + (v6 + v7));
        m = fmaxf(m, fmaxf(fmaxf(fmaxf(v0, v1), fmaxf(v2, v3)),
                           fmaxf(fmaxf(v4, v5), fmaxf(v6, v7))));
      }
    }
    for (; t < n; ++t) {
      int e = __builtin_amdgcn_readlane(eidv, t);
      if (lane < EO) {
        float v = ea[(size_t)e * EO + lane];
        s += v;
        m = fmaxf(m, v);
      }
    }
  }

  if (lane < EO) {
    if (deg == 0) m = 0.0f;
    float mean = s / (float)(deg > 0 ? deg : 1);
    unsigned short* row = featbf + (size_t)g * FEAT;
    row[lane]          = f2bf(s);
    row[EO + lane]     = f2bf(m);
    row[2 * EO + lane] = f2bf(mean);
  }
}

// ---------------- MFMA MLP: 64 nodes/block, 4 waves, 16 nodes/wave ----------------
__launch_bounds__(256)
__global__ void mlp_kernel(const unsigned short* __restrict__ featbf,
                           const unsigned short* __restrict__ W1T,
                           const unsigned short* __restrict__ W2T,
                           const float* __restrict__ b1,
                           const float* __restrict__ b2,
                           float* __restrict__ out) {
  __shared__ unsigned short h_lds[64][HID + 8];

  const int tid  = threadIdx.x;
  const int w    = tid >> 6;
  const int lane = tid & 63;
  const int llo  = lane & 15;
  const int lhi  = lane >> 4;

  const int g0   = blockIdx.x * 64;
  int rowA = g0 + w * 16 + llo;

  floatx4 acc[8];
#pragma unroll
  for (int c = 0; c < 8; ++c) acc[c] = (floatx4)0.0f;

  const unsigned short* arow = featbf + (size_t)rowA * FEAT;
#pragma unroll
  for (int ks = 0; ks < 5; ++ks) {
    short8 afrag = *(const short8*)(arow + ks * 32 + lhi * 8);
#pragma unroll
    for (int c = 0; c < 8; ++c) {
      short8 bfrag = *(const short8*)(W1T + (size_t)(c * 16 + llo) * K1 + ks * 32 + lhi * 8);
      acc[c] = __builtin_amdgcn_mfma_f32_16x16x32_bf16(afrag, bfrag, acc[c], 0, 0, 0);
    }
  }

#pragma unroll
  for (int c = 0; c < 8; ++c) {
    int col = c * 16 + llo;
    float bias = b1[col];
#pragma unroll
    for (int r = 0; r < 4; ++r) {
      int row = w * 16 + lhi * 4 + r;
      h_lds[row][col] = f2bf(fmaxf(acc[c][r] + bias, 0.0f));
    }
  }
  __syncthreads();

  floatx4 acc2[4];
#pragma unroll
  for (int c = 0; c < 4; ++c) acc2[c] = (floatx4)0.0f;

#pragma unroll
  for (int ks = 0; ks < 4; ++ks) {
    short8 afrag = *(const short8*)&h_lds[w * 16 + llo][ks * 32 + lhi * 8];
#pragma unroll
    for (int c = 0; c < 4; ++c) {
      short8 bfrag = *(const short8*)(W2T + (size_t)(c * 16 + llo) * HID + ks * 32 + lhi * 8);
      acc2[c] = __builtin_amdgcn_mfma_f32_16x16x32_bf16(afrag, bfrag, acc2[c], 0, 0, 0);
    }
  }

#pragma unroll
  for (int c = 0; c < 4; ++c) {
    int col = c * 16 + llo;
    float bias = b2[col];
#pragma unroll
    for (int r = 0; r < 4; ++r) {
      int g = g0 + w * 16 + lhi * 4 + r;
      if (g < N_NODES) out[(size_t)g * NOUT + col] = acc2[c][r] + bias;
    }
  }
}

extern "C" void kernel_launch(void* const* d_in, const int* in_sizes, int n_in,
                              void* d_out, int out_size, void* d_ws, size_t ws_size,
                              hipStream_t stream) {
  const int*   eidx = (const int*)d_in[1];
  const float* ea   = (const float*)d_in[2];
  const float* W1   = (const float*)d_in[5];
  const float* b1   = (const float*)d_in[6];
  const float* W2   = (const float*)d_in[7];
  const float* b2   = (const float*)d_in[8];
  const int* col = eidx + N_EDGES;  // edge_index[1]
  float* out = (float*)d_out;

  char* p = (char*)d_ws;
  int* cnt    = (int*)p;  p += (size_t)N_NODES * 4;
  int* pre    = (int*)p;  p += (size_t)N_NODES * 4;
  int* off    = (int*)p;  p += (size_t)N_NODES * 4;
  int* cursor = (int*)p;  p += (size_t)N_NODES * 4;
  int* bsum   = (int*)p;  p += 512;
  int* boff   = (int*)p;  p += 512;
  int* sorted_eid = (int*)p;  p += (size_t)N_EDGES * 4;
  unsigned short* featbf = (unsigned short*)p;  p += (size_t)FEAT_ROWS_ALLOC * FEAT * 2;
  unsigned short* W1T = (unsigned short*)p;     p += (size_t)HID * K1 * 2;
  unsigned short* W2T = (unsigned short*)p;

  init_prep_kernel<<<(N_NODES + 255) / 256, 256, 0, stream>>>(cnt, W1, W2, W1T, W2T);
  count_kernel<<<(N_EDGES / 4 + 255) / 256, 256, 0, stream>>>((const int4*)col, cnt);
  scan1_kernel<<<NB1, 256, 0, stream>>>(cnt, pre, bsum);
  scan2_kernel<<<1, 128, 0, stream>>>(bsum, boff);
  scan3_kernel<<<(N_NODES + 255) / 256, 256, 0, stream>>>(pre, boff, off, cursor);
  scatter_ids_kernel<<<(N_EDGES / 4 + 255) / 256, 256, 0, stream>>>((const int4*)col, cursor, sorted_eid);
  gather_kernel<<<(N_NODES + 3) / 4, 256, 0, stream>>>(ea, sorted_eid, off, cnt, featbf);
  mlp_kernel<<<(N_NODES + 63) / 64, 256, 0, stream>>>(featbf, W1T, W2T, b1, b2, out);
}